// Round 9
// baseline (341.837 us; speedup 1.0000x reference)
//
#include <hip/hip_runtime.h>

// Problem: L=200 events in pairs -> S=100 scan steps over u[N,N,3], N=256.
//
// r1-r8 post-mortem: kernel total ~105 us across scattered/staged/segmented/
// high-occupancy variants; HBM 1.45-1.55 TB/s invariant. Model: per-CU
// outstanding-line cap (~32 lines) x miss latency (~900cyc) = 5.5 GB/s/CU =
// 1.4 TB/s chip, occupancy-invariant. Only lever: latency (L2-prefetch hits
// at ~200cyc -> 24 GB/s/CU = 6.3 TB/s, cf. m13 copy). Our scan's per-block
// pattern (768B @ 768KB stride) defeats prefetch -> all-miss.
//
// Fix: sequentialize everything.
//  K1 fold_kernel (3200 blocks, full occupancy): per (s, 8-n chunk) compute
//     f[2s],f[2s+1] (each w/ev row read exactly once) and fold
//     g2[n][s][m][c] = a[2s,n,m,c]*f0 + a[2s+1,n,m,c]*f1.
//     Reads a as contiguous 24KB runs; writes g2 in scan-major layout.
//  K2 scan_kernel: block n streams g2[n][0..99] = 300KB CONTIGUOUS
//     (L2-prefetch regime), DD=20 static register ring, softmax chain.
//
// Layout: event_list[201,256,256], a[200,256,256,3], w[200,256,1,256],
//         u_begin[256,256,3], liner_w[256,3], liner_b[256], out[100,256,256].
// Workspace: g2 = 256*100*768*4 B = 78,643,200 B (ws is ~614 MB per fills).

#define NN 256
#define TT 200
#define SS 100
#define DD 20              // scan ring depth in steps (3 floats each)

// ---------------- kernel 1: fused f + fold, fully streaming ----------------
__global__ __launch_bounds__(256) void fold_kernel(
    const float* __restrict__ timep,   // [2]
    const float* __restrict__ ev,      // [201,N,N]
    const float* __restrict__ w,       // [T,N,1,N]
    const float* __restrict__ a,       // [T,N,N,3]
    float* __restrict__ g2)            // [N,S,768]
{
    const int s   = blockIdx.x;            // 0..99
    const int nc  = blockIdx.y;            // 0..31 (chunk of 8 n's)
    const int tid = threadIdx.x;
    const int lane = tid & 63;
    const int wv   = tid >> 6;             // 0..3

    __shared__ float f01[2][8];            // [t-parity][n-in-chunk]

    const int t0 = 2 * s, t1 = 2 * s + 1;
    const float tm0 = timep[0];
    const float tm1 = timep[1];

    // wave wv computes f for n-in-chunk {2wv, 2wv+1}, both parities
#pragma unroll
    for (int i = 0; i < 2; ++i) {
        const int nn = 2 * wv + i;         // 0..7
        const int n  = nc * 8 + nn;
        const size_t r0 = (size_t)t0 * (NN * NN) + (size_t)n * NN;
        const size_t r1 = (size_t)t1 * (NN * NN) + (size_t)n * NN;
        float4 w0 = ((const float4*)(w  + r0))[lane];
        float4 e0 = ((const float4*)(ev + r0))[lane];
        float4 w1 = ((const float4*)(w  + r1))[lane];
        float4 e1 = ((const float4*)(ev + r1))[lane];
        float d0 = w0.x * e0.x;
        d0 = fmaf(w0.y, e0.y, d0);
        d0 = fmaf(w0.z, e0.z, d0);
        d0 = fmaf(w0.w, e0.w, d0);
        float d1 = w1.x * e1.x;
        d1 = fmaf(w1.y, e1.y, d1);
        d1 = fmaf(w1.z, e1.z, d1);
        d1 = fmaf(w1.w, e1.w, d1);
#pragma unroll
        for (int o = 1; o < 64; o <<= 1) {
            d0 += __shfl_xor(d0, o, 64);
            d1 += __shfl_xor(d1, o, 64);
        }
        if (lane == 0) {
            f01[0][nn] = __expf(-d0 * tm0);
            f01[1][nn] = __expf(-d1 * tm1);
        }
    }
    __syncthreads();

    // fold: chunk = 8 n x 768 floats = 6144 floats = 1536 float4 per parity.
    // a-reads: two contiguous 24 KB runs. g2-writes: 768 B contiguous per n.
    const size_t ab0 = (size_t)t0 * (NN * NN * 3) + (size_t)(nc * 8) * (NN * 3);
    const size_t ab1 = (size_t)t1 * (NN * NN * 3) + (size_t)(nc * 8) * (NN * 3);
    const float4* pa0 = (const float4*)(a + ab0);
    const float4* pa1 = (const float4*)(a + ab1);

#pragma unroll
    for (int it = 0; it < 6; ++it) {                 // 1536 / 256
        const int e4  = it * 256 + tid;
        float4 a0 = pa0[e4];
        float4 a1 = pa1[e4];
        const int idx = e4 * 4;                      // float index in chunk
        const int nn  = idx / 768;                   // n-in-chunk (const per f4)
        const int rem = idx - nn * 768;
        const float f0 = f01[0][nn];
        const float f1 = f01[1][nn];
        float4 g;
        g.x = fmaf(a0.x, f0, a1.x * f1);
        g.y = fmaf(a0.y, f0, a1.y * f1);
        g.z = fmaf(a0.z, f0, a1.z * f1);
        g.w = fmaf(a0.w, f0, a1.w * f1);
        // regular store (NOT nontemporal): scan re-reads g2 via L2/L3 soon
        ((float4*)(g2 + (size_t)(nc * 8 + nn) * (SS * 768)
                      + (size_t)s * 768 + rem))[0] = g;
    }
}

// ---------------- kernel 2: the scan over a contiguous per-block stream ------
__global__ __launch_bounds__(256) void scan_kernel(
    const float* __restrict__ g2,      // [N,S,768]
    const float* __restrict__ ub,      // [N,N,3]
    const float* __restrict__ lw,      // [N,3]
    const float* __restrict__ lb,      // [N]
    float* __restrict__ out)           // [S,N,N]
{
    const int n = blockIdx.x;
    const int m = threadIdx.x;

    // this block's stream: 300 KB contiguous; this thread: 12 B per 768-B page
    const float* gp = g2 + (size_t)n * (SS * 768) + m * 3;

    const size_t cb = (size_t)n * (NN * 3) + (size_t)m * 3;
    float u0 = ub[cb + 0], u1 = ub[cb + 1], u2 = ub[cb + 2];
    const float w0 = lw[n * 3 + 0];
    const float w1 = lw[n * 3 + 1];
    const float w2 = lw[n * 3 + 2];
    const float bb = lb[n];

    // depth-DD static register ring (counted vmcnt from the compiler)
    float rg[DD][3];
#pragma unroll
    for (int j = 0; j < DD; ++j) {
        rg[j][0] = gp[j * 768 + 0];
        rg[j][1] = gp[j * 768 + 1];
        rg[j][2] = gp[j * 768 + 2];
    }

    float* op = out + (size_t)n * NN + m;

    for (int g = 0; g < SS / DD; ++g) {
        const int sb = g * DD;
#pragma unroll
        for (int j = 0; j < DD; ++j) {
            const int s = sb + j;
            float l0 = u0 + rg[j][0];
            float l1 = u1 + rg[j][1];
            float l2 = u2 + rg[j][2];
            if (g < SS / DD - 1) {       // refill slot for step s+DD
                rg[j][0] = gp[(s + DD) * 768 + 0];
                rg[j][1] = gp[(s + DD) * 768 + 1];
                rg[j][2] = gp[(s + DD) * 768 + 2];
            }
            float mx = fmaxf(l0, fmaxf(l1, l2));
            float e0 = __expf(l0 - mx);
            float e1 = __expf(l1 - mx);
            float e2 = __expf(l2 - mx);
            float iv = __builtin_amdgcn_rcpf(e0 + e1 + e2);
            u0 = e0 * iv;
            u1 = e1 * iv;
            u2 = e2 * iv;
            __builtin_nontemporal_store(
                fmaf(u0, w0, fmaf(u1, w1, fmaf(u2, w2, bb))),
                op + (size_t)s * (NN * NN));
        }
    }
}

extern "C" void kernel_launch(void* const* d_in, const int* in_sizes, int n_in,
                              void* d_out, int out_size, void* d_ws, size_t ws_size,
                              hipStream_t stream) {
    const float* timep = (const float*)d_in[0];
    const float* ev    = (const float*)d_in[1];
    const float* ub    = (const float*)d_in[2];
    const float* a     = (const float*)d_in[3];
    const float* w     = (const float*)d_in[4];
    const float* lw    = (const float*)d_in[5];
    const float* lb    = (const float*)d_in[6];
    float* out = (float*)d_out;
    float* g2  = (float*)d_ws;               // needs 78,643,200 B (ws ~614 MB)

    fold_kernel<<<dim3(SS, 32), 256, 0, stream>>>(timep, ev, w, a, g2);
    scan_kernel<<<NN, 256, 0, stream>>>(g2, ub, lw, lb, out);
}

// Round 11
// 308.367 us; speedup vs baseline: 1.1085x; 1.1085x over previous
//
#include <hip/hip_runtime.h>

// Problem: L=200 events in pairs -> S=100 scan steps over u[N,N,3], N=256.
//
// r1-r9 model: read BW ceiling ~3.1-3.3 TB/s chip-wide (12.3 GB/s/CU),
// pattern/occupancy/staging-invariant (6 structures agree; m13 copy's read
// half = 3.15). Compulsory reads 262 MB -> 83 us kernel floor. r1/r7 at
// 101-108 us lose ~18 us to phase serialization (w/ev prologue THEN a-scan,
// one stream idle at a time). This round (resubmit of r9 after infra
// timeout; audited: phase algebra exact, barriers uniform, fs2 race-free,
// ~110-130 VGPR no spill): single pass with BOTH streams in flight the
// whole kernel: 26 phases, each = {load next phase's w/ev rows to regs
// (in flight across raw s_barrier - no vmcnt drain for reg loads), reduce
// current rows -> fs2[4q+wv] (float2, exactly next phase's 4 steps),
// 4 scan steps from static register ring (RD=8, refill s+8)}.
//
// Layout: event_list[201,256,256], a[200,256,256,3], w[200,256,1,256],
//         u_begin[256,256,3], liner_w[256,3], liner_b[256], out[100,256,256].

#define NN 256
#define TT 200
#define SS 100
#define RD 8               // a-ring depth in steps (6 floats each)

__global__ __launch_bounds__(256) void fused_kernel(
    const float* __restrict__ timep,   // [2]
    const float* __restrict__ ev,      // [201,N,N]
    const float* __restrict__ ub,      // [N,N,3]
    const float* __restrict__ a,       // [T,N,N,3]
    const float* __restrict__ w,       // [T,N,1,N]
    const float* __restrict__ lw,      // [N,3]
    const float* __restrict__ lb,      // [N]
    float* __restrict__ out)           // [S,N,N]
{
    __shared__ float2 fs2[SS];         // fs2[s] = {f[2s], f[2s+1]}

    const int n    = blockIdx.x;
    const int tid  = threadIdx.x;
    const int lane = tid & 63;
    const int wv   = tid >> 6;         // wave 0..3

    const float tm0 = timep[0];
    const float tm1 = timep[1];

    const float* wrow = w  + (size_t)n * NN;
    const float* erow = ev + (size_t)n * NN;

    float4 wA, eA, wB, eB, wC, eC, wD, eD;

    // rows (TB, TB+1): w and ev, 1 float4/lane each (1 KB/row/instruction)
#define LOADROWS(WX, EX, WY, EY, TB)                                           \
    do {                                                                       \
        const size_t r0_ = (size_t)(TB) * (NN * NN);                           \
        WX = ((const float4*)(wrow + r0_))[lane];                              \
        EX = ((const float4*)(erow + r0_))[lane];                              \
        WY = ((const float4*)(wrow + r0_ + NN * NN))[lane];                    \
        EY = ((const float4*)(erow + r0_ + NN * NN))[lane];                    \
    } while (0)

    // phase-0 rows first (latency-critical for phase-0 reduce)
    LOADROWS(wA, eA, wB, eB, 2 * wv);

    // a-ring preload: steps 0..RD-1 (static indices -> fixed VGPRs)
    const size_t TS = (size_t)NN * NN * 3;
    const size_t cb = (size_t)n * (NN * 3) + (size_t)tid * 3;
    const float* ab = a + cb;
    float rg[RD][6];
#pragma unroll
    for (int j = 0; j < RD; ++j) {
        const float* p_ = ab + (size_t)(2 * j) * TS;
        rg[j][0] = p_[0];      rg[j][1] = p_[1];      rg[j][2] = p_[2];
        rg[j][3] = p_[TS + 0]; rg[j][4] = p_[TS + 1]; rg[j][5] = p_[TS + 2];
    }

    float u0 = ub[cb + 0], u1 = ub[cb + 1], u2 = ub[cb + 2];
    const float w0 = lw[n * 3 + 0];
    const float w1 = lw[n * 3 + 1];
    const float w2 = lw[n * 3 + 2];
    const float bb = lb[n];
    float* op = out + (size_t)n * NN + tid;

    // reduce rows (t=8Q+2wv even -> time[0]; t+1 odd -> time[1]);
    // one float2 per wave per phase = next phase's step s = 4Q+wv.
#define REDUCE(WX, EX, WY, EY, Q)                                              \
    do {                                                                       \
        float d0_ = WX.x * EX.x;                                               \
        d0_ = fmaf(WX.y, EX.y, d0_);                                           \
        d0_ = fmaf(WX.z, EX.z, d0_);                                           \
        d0_ = fmaf(WX.w, EX.w, d0_);                                           \
        float d1_ = WY.x * EY.x;                                               \
        d1_ = fmaf(WY.y, EY.y, d1_);                                           \
        d1_ = fmaf(WY.z, EY.z, d1_);                                           \
        d1_ = fmaf(WY.w, EY.w, d1_);                                           \
        _Pragma("unroll")                                                      \
        for (int o_ = 1; o_ < 64; o_ <<= 1) {                                  \
            d0_ += __shfl_xor(d0_, o_, 64);                                    \
            d1_ += __shfl_xor(d1_, o_, 64);                                    \
        }                                                                      \
        if (lane == 0)                                                         \
            fs2[4 * (Q) + wv] =                                                \
                make_float2(__expf(-d0_ * tm0), __expf(-d1_ * tm1));           \
    } while (0)

    // raw barrier: drains LDS (fs2 writes) but NOT vmcnt -> register loads
    // stay in flight across phases. sched_barrier pins code motion.
#define FENCE_BAR                                                              \
    do {                                                                       \
        asm volatile("s_waitcnt lgkmcnt(0)" ::: "memory");                     \
        __builtin_amdgcn_s_barrier();                                          \
        __builtin_amdgcn_sched_barrier(0);                                     \
    } while (0)

#define STEP(S, J, RF)                                                         \
    do {                                                                       \
        const float2 ff_ = fs2[(S)];                                           \
        float l0_ = fmaf(rg[J][0], ff_.x, fmaf(rg[J][3], ff_.y, u0));          \
        float l1_ = fmaf(rg[J][1], ff_.x, fmaf(rg[J][4], ff_.y, u1));          \
        float l2_ = fmaf(rg[J][2], ff_.x, fmaf(rg[J][5], ff_.y, u2));          \
        if (RF) { /* refill slot J with step S+RD (uniform branch) */          \
            const float* pR_ = ab + (size_t)(2 * ((S) + RD)) * TS;             \
            rg[J][0] = pR_[0];                                                 \
            rg[J][1] = pR_[1];                                                 \
            rg[J][2] = pR_[2];                                                 \
            rg[J][3] = pR_[TS + 0];                                            \
            rg[J][4] = pR_[TS + 1];                                            \
            rg[J][5] = pR_[TS + 2];                                            \
        }                                                                      \
        float mx_ = fmaxf(l0_, fmaxf(l1_, l2_));                               \
        float e0_ = __expf(l0_ - mx_);                                         \
        float e1_ = __expf(l1_ - mx_);                                         \
        float e2_ = __expf(l2_ - mx_);                                         \
        float iv_ = __builtin_amdgcn_rcpf(e0_ + e1_ + e2_);                    \
        u0 = e0_ * iv_;                                                        \
        u1 = e1_ * iv_;                                                        \
        u2 = e2_ * iv_;                                                        \
        __builtin_nontemporal_store(                                           \
            fmaf(u0, w0, fmaf(u1, w1, fmaf(u2, w2, bb))),                      \
            op + (size_t)(S) * (NN * NN));                                     \
    } while (0)

    // ---- phase 0: reduce rows 0..7, prefetch rows 8..15, no steps ----
    LOADROWS(wC, eC, wD, eD, 8 + 2 * wv);
    REDUCE(wA, eA, wB, eB, 0);
    FENCE_BAR;

    // ---- pairs of phases (2i-1, 2i), i=1..12 ----
    // odd phase: reduce C/D, load A/B, steps -> ring slots 0..3
    // even phase: reduce A/B, load C/D, steps -> ring slots 4..7
    for (int i = 1; i <= 12; ++i) {
        const int qo = 2 * i - 1;
        LOADROWS(wA, eA, wB, eB, 8 * (qo + 1) + 2 * wv);
        REDUCE(wC, eC, wD, eD, qo);
        FENCE_BAR;
        {
            const int s0 = 4 * (qo - 1);
            STEP(s0 + 0, 0, 1);
            STEP(s0 + 1, 1, 1);
            STEP(s0 + 2, 2, 1);
            STEP(s0 + 3, 3, 1);
        }
        const int qe  = 2 * i;
        const int tnx = (qe < 24) ? (8 * (qe + 1)) : 0;   // qe=24: dummy rows
        LOADROWS(wC, eC, wD, eD, tnx + 2 * wv);
        REDUCE(wA, eA, wB, eB, qe);
        FENCE_BAR;
        {
            const int s0 = 4 * (qe - 1);
            const int rf = (qe != 24);    // s+8 > 99 only in phase 24
            STEP(s0 + 0, 4, rf);
            STEP(s0 + 1, 5, rf);
            STEP(s0 + 2, 6, rf);
            STEP(s0 + 3, 7, rf);
        }
    }

    // ---- phase 25: steps 96..99 (f written in phase 24, barrier already
    //      crossed at phase 24's FENCE_BAR; slots 0..3 filled in phase 23) ----
    STEP(96, 0, 0);
    STEP(97, 1, 0);
    STEP(98, 2, 0);
    STEP(99, 3, 0);

#undef STEP
#undef FENCE_BAR
#undef REDUCE
#undef LOADROWS
}

extern "C" void kernel_launch(void* const* d_in, const int* in_sizes, int n_in,
                              void* d_out, int out_size, void* d_ws, size_t ws_size,
                              hipStream_t stream) {
    const float* timep = (const float*)d_in[0];
    const float* ev    = (const float*)d_in[1];
    const float* ub    = (const float*)d_in[2];
    const float* a     = (const float*)d_in[3];
    const float* w     = (const float*)d_in[4];
    const float* lw    = (const float*)d_in[5];
    const float* lb    = (const float*)d_in[6];
    float* out = (float*)d_out;

    fused_kernel<<<NN, 256, 0, stream>>>(timep, ev, ub, a, w, lw, lb, out);
}